// Round 1
// baseline (15.034 us; speedup 1.0000x reference)
//
#include <hip/hip_runtime.h>

// Problem: DIM=64, N=64, M=2*DIM*N+1=8193
//   mat:          (DIM, N)  f32   mat[d*64 + n]
//   weights_sort: (M, DIM)  f32   ws[m*64 + d]
//   weights_dot:  (M, N)    f32   wd[m*64 + n]
// reference:
//   s[n,m]   = sum_d mat[d,n] * ws[m,d]
//   col_sorted[:,m] = sort(s[:,m])          (ascending over n)
//   out[m]   = sum_n wd[m,n] * col_sorted[n,m]
//
// Strategy: one 64-lane wave per m. Lane n holds s[n]; bitonic sort across
// the wave via __shfl_xor; wave-reduce the final dot.

#define DIMC 64
#define NC   64
#define MC   8193

__global__ __launch_bounds__(256) void embed_kernel(
    const float* __restrict__ mat,
    const float* __restrict__ ws,
    const float* __restrict__ wd,
    float* __restrict__ out)
{
    const int lane = threadIdx.x & 63;
    const int m = blockIdx.x * 4 + (threadIdx.x >> 6);
    if (m >= MC) return;

    // Coalesced load of this wave's weights_sort row: lane d holds ws[m][d].
    const float wsv = ws[m * DIMC + lane];

    // s[lane] = sum_d mat[d][lane] * ws[m][d]
    // mat loads are coalesced per d (lane-contiguous) and L1-resident (16 KB).
    // __shfl with compile-time-uniform source lane -> cheap uniform broadcast.
    float s = 0.0f;
#pragma unroll
    for (int d = 0; d < DIMC; ++d) {
        s = fmaf(mat[d * NC + lane], __shfl(wsv, d), s);
    }

    // Bitonic sort ascending across the 64 lanes.
    // For merge size k, stride j: lanes i and i^j compare-exchange;
    // ascending segment iff (i & k)==0; lower lane keeps min in ascending.
#pragma unroll
    for (int k = 2; k <= 64; k <<= 1) {
#pragma unroll
        for (int j = k >> 1; j > 0; j >>= 1) {
            const float partner = __shfl_xor(s, j);
            const bool up = ((lane & k) == 0);
            const bool keep_min = (((lane & j) == 0) == up);
            s = keep_min ? fminf(s, partner) : fmaxf(s, partner);
        }
    }
    // (k==64: lane&64==0 for all lanes -> final merge ascending over all 64)

    // out[m] = sum_n wd[m][n] * sorted[n]
    float prod = wd[m * NC + lane] * s;
#pragma unroll
    for (int off = 32; off > 0; off >>= 1) {
        prod += __shfl_xor(prod, off);
    }
    if (lane == 0) out[m] = prod;
}

extern "C" void kernel_launch(void* const* d_in, const int* in_sizes, int n_in,
                              void* d_out, int out_size, void* d_ws, size_t ws_size,
                              hipStream_t stream) {
    const float* mat = (const float*)d_in[0];
    const float* ws  = (const float*)d_in[1];
    const float* wd  = (const float*)d_in[2];
    float* out = (float*)d_out;

    const int waves_per_block = 4;                       // 256 threads
    const int grid = (MC + waves_per_block - 1) / waves_per_block;  // 2049
    embed_kernel<<<grid, 256, 0, stream>>>(mat, ws, wd, out);
}

// Round 2
// 11.028 us; speedup vs baseline: 1.3632x; 1.3632x over previous
//
#include <hip/hip_runtime.h>

// Problem: DIM=64, N=64, M=2*DIM*N+1=8193
//   mat:          (DIM, N)  f32   mat[d*64 + n]
//   weights_sort: (M, DIM)  f32   ws[m*64 + d]
//   weights_dot:  (M, N)    f32   wd[m*64 + n]
// reference:
//   s[n,m]   = sum_d mat[d,n] * ws[m,d]
//   col_sorted[:,m] = sort(s[:,m])          (ascending over n)
//   out[m]   = sum_n wd[m,n] * col_sorted[n,m]
//
// Strategy: one 64-lane wave per m. Lane n holds s[n]; bitonic sort across
// the wave via __shfl_xor; wave-reduce the final dot.
//
// R1 change: m is readfirstlane'd -> ws row address is fully scalar ->
// compiler emits s_load_dwordx16 for the 64-float ws row instead of 64
// ds_bpermute broadcasts (DS ops/wave: 91 -> 27). 4-way accumulator split
// breaks the 64-deep serial FMA dependency chain.

#define DIMC 64
#define NC   64
#define MC   8193
#define WPB  4   // waves per block (256 threads)

__global__ __launch_bounds__(256) void embed_kernel(
    const float* __restrict__ mat,
    const float* __restrict__ ws,
    const float* __restrict__ wd,
    float* __restrict__ out)
{
    const int lane = threadIdx.x & 63;
    // Wave-uniform m, provably so for the compiler -> scalar loads for ws row.
    const int m = __builtin_amdgcn_readfirstlane(blockIdx.x * WPB + (threadIdx.x >> 6));
    if (m >= MC) return;

    const float* __restrict__ wsrow = ws + m * DIMC;  // uniform address

    // s[lane] = sum_d mat[d][lane] * ws[m][d]
    // mat loads: one coalesced wave load per d, L1-resident (16 KB total).
    // wsrow[d]: scalar (SGPR) loads, zero DS/VALU broadcast cost.
    float s0 = 0.0f, s1 = 0.0f, s2 = 0.0f, s3 = 0.0f;
#pragma unroll
    for (int d = 0; d < DIMC; d += 4) {
        s0 = fmaf(mat[(d + 0) * NC + lane], wsrow[d + 0], s0);
        s1 = fmaf(mat[(d + 1) * NC + lane], wsrow[d + 1], s1);
        s2 = fmaf(mat[(d + 2) * NC + lane], wsrow[d + 2], s2);
        s3 = fmaf(mat[(d + 3) * NC + lane], wsrow[d + 3], s3);
    }
    float s = (s0 + s1) + (s2 + s3);

    // Bitonic sort ascending across the 64 lanes (21 compare-exchanges).
#pragma unroll
    for (int k = 2; k <= 64; k <<= 1) {
#pragma unroll
        for (int j = k >> 1; j > 0; j >>= 1) {
            const float partner = __shfl_xor(s, j);
            const bool up = ((lane & k) == 0);
            const bool keep_min = (((lane & j) == 0) == up);
            s = keep_min ? fminf(s, partner) : fmaxf(s, partner);
        }
    }

    // out[m] = sum_n wd[m][n] * sorted[n]
    float prod = wd[m * NC + lane] * s;
#pragma unroll
    for (int off = 32; off > 0; off >>= 1) {
        prod += __shfl_xor(prod, off);
    }
    if (lane == 0) out[m] = prod;
}

extern "C" void kernel_launch(void* const* d_in, const int* in_sizes, int n_in,
                              void* d_out, int out_size, void* d_ws, size_t ws_size,
                              hipStream_t stream) {
    const float* mat = (const float*)d_in[0];
    const float* ws  = (const float*)d_in[1];
    const float* wd  = (const float*)d_in[2];
    float* out = (float*)d_out;

    const int grid = (MC + WPB - 1) / WPB;  // 2049 blocks of 256 threads
    embed_kernel<<<grid, 256, 0, stream>>>(mat, ws, wd, out);
}